// Round 3
// baseline (487.823 us; speedup 1.0000x reference)
//
#include <hip/hip_runtime.h>

#define N_ENTITIES 500000
#define N_RELS 1000
#define EMB_DIM 128
#define N_TRIPLES 1000000

// Apply-kernel tiling: each 256-thread block owns a contiguous 32-row tile
// (32 x 512 B = 16 KB); step i covers 8 consecutive rows -> 1 KB bursts per
// wave. 500000 / 32 = 15625 blocks exactly.
#define STEPS 4
#define ROWS_PER_STEP 8
#define BLOCK_ROWS (STEPS * ROWS_PER_STEP)

typedef float floatx4 __attribute__((ext_vector_type(4)));
typedef unsigned long long u64;

// pack[v << padShift] encodes the winning triple for entity v, pre-joined:
//   key = (e+1)<<29 | r<<19 | t      (t < 2^19, r < 2^10, e+1 < 2^20)
//   0   = no winner
// max over keys == max over e (e in high bits) => last-write-wins,
// order-independent => deterministic under graph replay.
//
// padShift spreads entities across cache lines (padShift=3 -> one entity per
// 64 B line). Theory: the device-scope atomic unit serializes same-line RMWs;
// at stride 1 there are ~16 atomics/line (1M over 65536 lines). Padding cuts
// collisions 8x. Chosen at runtime from ws_size, falling back to stride 1.

__global__ void init_pack_kernel(ulonglong2* __restrict__ pack2, int n2) {
    int i = blockIdx.x * blockDim.x + threadIdx.x;
    if (i < n2) {
        ulonglong2 z; z.x = 0ull; z.y = 0ull;
        pack2[i] = z;
    }
}

__global__ void find_winner_kernel(const int4* __restrict__ h4,
                                   const int4* __restrict__ r4,
                                   const int4* __restrict__ t4,
                                   u64* __restrict__ pack,
                                   int padShift) {
    int q = blockIdx.x * blockDim.x + threadIdx.x;  // quad of triples
    if (q >= N_TRIPLES / 4) return;
    int4 h = h4[q];
    int4 r = r4[q];
    int4 t = t4[q];
    u64 e1 = (u64)(4 * q + 1);
    atomicMax(&pack[(size_t)h.x << padShift], (e1      << 29) | ((u64)r.x << 19) | (u64)t.x);
    atomicMax(&pack[(size_t)h.y << padShift], ((e1 + 1) << 29) | ((u64)r.y << 19) | (u64)t.y);
    atomicMax(&pack[(size_t)h.z << padShift], ((e1 + 2) << 29) | ((u64)r.z << 19) | (u64)t.z);
    atomicMax(&pack[(size_t)h.w << padShift], ((e1 + 3) << 29) | ((u64)r.w << 19) | (u64)t.w);
}

// One row = 128 floats = 32 lanes x float4. Each thread handles 4 rows within
// its block's contiguous 32-row tile. Chain per row: pack (streamed, NT so the
// pack stream doesn't evict the memory stream from L3) -> {rv,tv} gathers;
// t-gathers hit L3 because the memory stream passes through it and out-stores
// are nontemporal (no L3 eviction). FETCH currently shows ~zero gather
// over-fetch -- preserve that property.
__global__ void apply_kernel(const float* __restrict__ memory,
                             const float* __restrict__ rel_table,
                             const u64* __restrict__ pack,
                             float* __restrict__ out,
                             int padShift) {
    int lane = threadIdx.x & 31;
    int hr   = threadIdx.x >> 5;                    // 0..7: half-wave index
    int base = blockIdx.x * BLOCK_ROWS;

    int rows[STEPS];
    u64 k[STEPS];
#pragma unroll
    for (int i = 0; i < STEPS; ++i) {
        rows[i] = base + i * ROWS_PER_STEP + hr;    // contiguous per step
        k[i] = __builtin_nontemporal_load(&pack[(size_t)rows[i] << padShift]);
    }

    floatx4 h[STEPS];
#pragma unroll
    for (int i = 0; i < STEPS; ++i)
        h[i] = ((const floatx4*)(memory + (size_t)rows[i] * EMB_DIM))[lane];

    floatx4 rv[STEPS], tv[STEPS];
#pragma unroll
    for (int i = 0; i < STEPS; ++i) {
        int t = (int)(k[i] & 0x7FFFF);              // row 0 when no winner
        int r = (int)((k[i] >> 19) & 0x3FF);        // rel 0 when no winner
        rv[i] = ((const floatx4*)(rel_table + (size_t)r * EMB_DIM))[lane];
        tv[i] = ((const floatx4*)(memory    + (size_t)t * EMB_DIM))[lane];
    }

#pragma unroll
    for (int i = 0; i < STEPS; ++i) {
        // Exact arithmetic of the verified kernel for winner rows; exact h
        // passthrough for non-winner rows (select, not scale-by-0).
        floatx4 upd = 0.9f * h[i] + 0.1f * (h[i] + rv[i] - tv[i]);
        floatx4 val = (k[i] != 0ull) ? upd : h[i];
        floatx4* orow = (floatx4*)(out + (size_t)rows[i] * EMB_DIM) + lane;
        __builtin_nontemporal_store(val, orow);
    }
}

extern "C" void kernel_launch(void* const* d_in, const int* in_sizes, int n_in,
                              void* d_out, int out_size, void* d_ws, size_t ws_size,
                              hipStream_t stream) {
    const float* memory    = (const float*)d_in[0];
    const float* rel_table = (const float*)d_in[1];
    const int*   h_idx     = (const int*)d_in[2];
    const int*   r_idx     = (const int*)d_in[3];
    const int*   t_idx     = (const int*)d_in[4];
    float*       out       = (float*)d_out;

    u64* pack = (u64*)d_ws;

    // Largest per-entity stride (in u64s, power of two) that fits d_ws.
    size_t base_bytes = (size_t)N_ENTITIES * sizeof(u64);
    int padShift = 0;
    if      (ws_size >= base_bytes * 8) padShift = 3;   // 64 B/entity, 32 MB
    else if (ws_size >= base_bytes * 4) padShift = 2;
    else if (ws_size >= base_bytes * 2) padShift = 1;

    {
        long long n_u64 = (long long)N_ENTITIES << padShift;
        int n2 = (int)(n_u64 / 2);                  // N_ENTITIES even
        int threads = 256;
        int blocks = (n2 + threads - 1) / threads;
        init_pack_kernel<<<blocks, threads, 0, stream>>>((ulonglong2*)pack, n2);
    }
    {
        int threads = 256;
        int quads = N_TRIPLES / 4;
        int blocks = (quads + threads - 1) / threads;
        find_winner_kernel<<<blocks, threads, 0, stream>>>(
            (const int4*)h_idx, (const int4*)r_idx, (const int4*)t_idx,
            pack, padShift);
    }
    {
        int threads = 256;
        int blocks = N_ENTITIES / BLOCK_ROWS;       // 15625 exact
        apply_kernel<<<blocks, threads, 0, stream>>>(memory, rel_table, pack,
                                                     out, padShift);
    }
}